// Round 6
// baseline (536.540 us; speedup 1.0000x reference)
//
#include <hip/hip_runtime.h>

#define V_N 30000
#define E_N 500000

__device__ __forceinline__ float lrelu(float x) { return fmaxf(x, 0.2f * x); }

// t + dpp_permuted(t); masked-off rows contribute 0.
template<int CTRL, int RMASK>
__device__ __forceinline__ float dpp_add(float t) {
    int b = __builtin_amdgcn_update_dpp(0, __float_as_int(t), CTRL, RMASK, 0xF, true);
    return t + __int_as_float(b);
}

// Input: value on lanes 0-31 (lanes 32-63 must hold 0).
// Output: lanes 32-63 all hold the sum over lanes 0-31. (VALU-only, 0 DS ops)
__device__ __forceinline__ float rowsum_to_high(float t) {
    t = dpp_add<0x121, 0xF>(t);   // row_ror:1
    t = dpp_add<0x122, 0xF>(t);   // row_ror:2
    t = dpp_add<0x124, 0xF>(t);   // row_ror:4
    t = dpp_add<0x128, 0xF>(t);   // row_ror:8  -> each lane = its 16-row sum
    t = dpp_add<0x142, 0xA>(t);   // row_bcast15 -> lanes16-31 = full 32-sum
    t = dpp_add<0x143, 0xC>(t);   // row_bcast31 -> lanes32-63 (+0) = full sum
    return t;
}

// low half gets the high half's value; high half keeps its own.
__device__ __forceinline__ float spread_high(float v, int half) {
    float sw = __shfl_xor(v, 32, 64);
    return half ? v : sw;
}

// ---------------------------------------------------------------------------
// Kernel A: node transforms — wave per node, weights in VGPRs, scalar x loads.
// tab layout per node (256 f = 1 KB): [f*4+h] = att[h][f], [128+f*4+h] = msg[h][f]
// low half computes src-side (Was/Wms), high half dst-side (Wad/Wmd).
// ---------------------------------------------------------------------------
__global__ __launch_bounds__(256) void node_xform(
    const float* __restrict__ nf,
    const float* __restrict__ Was, const float* __restrict__ bas,
    const float* __restrict__ Wad, const float* __restrict__ bad,
    const float* __restrict__ Wms, const float* __restrict__ bms,
    const float* __restrict__ Wmd, const float* __restrict__ bmd,
    float* __restrict__ tab_s, float* __restrict__ tab_d)
{
    int tid  = threadIdx.x;
    int lane = tid & 63, half = (tid >> 5) & 1, l32 = tid & 31;
    float wA[32], wB[32];
    #pragma unroll
    for (int k = 0; k < 32; ++k) {
        wA[k] = half ? Wad[k * 32 + l32] : Was[k * 32 + l32];
        wB[k] = half ? Wmd[k * 32 + l32] : Wms[k * 32 + l32];
    }
    float bA = half ? bad[l32] : bas[l32];
    float bB = half ? bmd[l32] : bms[l32];
    int wid    = (blockIdx.x * 256 + tid) >> 6;
    int nwaves = (gridDim.x * 256) >> 6;
    for (int n = wid; n < V_N; n += nwaves) {
        int nu = __builtin_amdgcn_readfirstlane(n);
        float* base = (half ? tab_d : tab_s) + (size_t)nu * 256;
        #pragma unroll
        for (int h = 0; h < 4; ++h) {
            const float* xr = nf + (size_t)nu * 128 + h * 32;  // wave-uniform
            float aA = bA, aB = bB;
            #pragma unroll
            for (int k = 0; k < 32; ++k) {
                float xk = xr[k];
                aA = fmaf(xk, wA[k], aA);
                aB = fmaf(xk, wB[k], aB);
            }
            base[l32 * 4 + h]       = aA;   // att
            base[128 + l32 * 4 + h] = aB;   // msg
        }
    }
}

// ---------------------------------------------------------------------------
// CSR build: histogram -> exclusive scan -> scatter edge ids by dst.
// ---------------------------------------------------------------------------
__global__ __launch_bounds__(256) void hist_k(
    const int* __restrict__ dst, int* __restrict__ deg)
{
    int i = blockIdx.x * 256 + threadIdx.x;
    if (i < E_N) atomicAdd(&deg[dst[i]], 1);
}

__global__ __launch_bounds__(1024) void scan_k(
    const int* __restrict__ deg, int* __restrict__ rowptr, int* __restrict__ cursor)
{
    __shared__ int wsum[16];
    __shared__ int carry_s;
    int tid = threadIdx.x;
    int lane = tid & 63, wv = tid >> 6;
    if (tid == 0) carry_s = 0;
    __syncthreads();
    for (int base = 0; base < V_N; base += 1024) {
        int i = base + tid;
        int v = (i < V_N) ? deg[i] : 0;
        int x = v;
        #pragma unroll
        for (int off = 1; off < 64; off <<= 1) {
            int t = __shfl_up(x, off, 64);
            if (lane >= off) x += t;
        }
        if (lane == 63) wsum[wv] = x;
        __syncthreads();
        if (wv == 0 && lane < 16) {
            int s = wsum[lane];
            #pragma unroll
            for (int off = 1; off < 16; off <<= 1) {
                int t = __shfl_up(s, off, 64);
                if (lane >= off) s += t;
            }
            wsum[lane] = s;
        }
        __syncthreads();
        int woff  = (wv == 0) ? 0 : wsum[wv - 1];
        int carry = carry_s;
        int excl  = carry + woff + x - v;
        if (i < V_N) { rowptr[i] = excl; cursor[i] = excl; }
        __syncthreads();
        if (tid == 1023) carry_s = carry + wsum[15];
        __syncthreads();
    }
    if (tid == 0) rowptr[V_N] = carry_s;
}

__global__ __launch_bounds__(256) void scatter_k(
    const int* __restrict__ dst, int* __restrict__ cursor, int* __restrict__ eidx)
{
    int i = blockIdx.x * 256 + threadIdx.x;
    if (i < E_N) {
        int p = atomicAdd(&cursor[dst[i]], 1);
        eidx[p] = i;
    }
}

// ---------------------------------------------------------------------------
// Kernel B: per-dst aggregation, ONE NODE PER WAVE, work-queue balanced.
// lanes 0-31: attention path (ea, scores); lanes 32-63: message path (me, m).
// Edge GEMV: scalar(SGPR)-broadcast x, weight columns in VGPRs -> 0 DS ops.
// Score reduce: DPP (VALU pipe), result deposited on the msg half.
// b_dot omitted: constant per-dst shift cancels exactly in softmax.
// ---------------------------------------------------------------------------
__global__ __launch_bounds__(256) void node_gather(
    const float* __restrict__ ef, const int* __restrict__ src,
    const int* __restrict__ rowptr, const int* __restrict__ eidx,
    const float* __restrict__ Wae, const float* __restrict__ bae,
    const float* __restrict__ Wdot,
    const float* __restrict__ Wme, const float* __restrict__ bme,
    const float* __restrict__ Wwn, const float* __restrict__ bwn,
    const float* __restrict__ nf,
    const float* __restrict__ tab_s, const float* __restrict__ tab_d,
    int* __restrict__ qctr,
    float* __restrict__ out)
{
    int tid  = threadIdx.x;
    int lane = tid & 63, half = (tid >> 5) & 1, l32 = tid & 31;
    float wreg[32], wwreg[32];
    #pragma unroll
    for (int k = 0; k < 32; ++k) {
        wreg[k]  = half ? Wme[k * 32 + l32] : Wae[k * 32 + l32];
        wwreg[k] = Wwn[k * 32 + l32];
    }
    float bam = half ? bme[l32] : bae[l32];
    float wdl = half ? 0.f : Wdot[l32];      // high half contributes 0 to score
    float bw  = bwn[l32];

    for (;;) {
        int n0 = 0;
        if (lane == 0) n0 = atomicAdd(qctr, 1);
        int n = __builtin_amdgcn_readfirstlane(__shfl(n0, 0, 64));
        if (n >= V_N) break;

        const float4 d4 = *(const float4*)(tab_d + (size_t)n * 256 + lane * 4);
        float acc0 = 0.f, acc1 = 0.f, acc2 = 0.f, acc3 = 0.f;
        float s0 = 0.f, s1 = 0.f, s2 = 0.f, s3 = 0.f;
        int p0 = __builtin_amdgcn_readfirstlane(rowptr[n]);
        int p1 = __builtin_amdgcn_readfirstlane(rowptr[n + 1]);

        int e = 0;
        float4 g4 = make_float4(0.f, 0.f, 0.f, 0.f);
        if (p0 < p1) {
            e = __builtin_amdgcn_readfirstlane(eidx[p0]);
            int si = __builtin_amdgcn_readfirstlane(src[e]);
            g4 = *(const float4*)(tab_s + (size_t)si * 256 + lane * 4);
        }
        for (int p = p0; p < p1; ++p) {
            int ec = e; float4 c4 = g4;
            if (p + 1 < p1) {                      // prefetch next edge
                e = __builtin_amdgcn_readfirstlane(eidx[p + 1]);
                int si = __builtin_amdgcn_readfirstlane(src[e]);
                g4 = *(const float4*)(tab_s + (size_t)si * 256 + lane * 4);
            }
            // edge GEMV: scalar-broadcast x, VGPR weights (ea on low, me on high)
            const float* xr = ef + (size_t)ec * 32;     // wave-uniform address
            float am = bam;
            #pragma unroll
            for (int k = 0; k < 32; ++k) am = fmaf(xr[k], wreg[k], am);
            // low: e_att = lrelu(sa+da+ea); high: m = lrelu(sm+dm+me)
            float v0 = lrelu(c4.x + d4.x + am);
            float v1 = lrelu(c4.y + d4.y + am);
            float v2 = lrelu(c4.z + d4.z + am);
            float v3 = lrelu(c4.w + d4.w + am);
            // scores: reduce (v*wd) over low half, deposit onto high half
            float t0 = rowsum_to_high(v0 * wdl);
            float t1 = rowsum_to_high(v1 * wdl);
            float t2 = rowsum_to_high(v2 * wdl);
            float t3 = rowsum_to_high(v3 * wdl);
            float x0 = __expf(t0), x1 = __expf(t1);
            float x2 = __expf(t2), x3 = __expf(t3);
            s0 += x0; s1 += x1; s2 += x2; s3 += x3;         // valid on high half
            acc0 = fmaf(x0, v0, acc0);                      // valid on high half
            acc1 = fmaf(x1, v1, acc1);
            acc2 = fmaf(x2, v2, acc2);
            acc3 = fmaf(x3, v3, acc3);
        }
        // make acc/s valid on all lanes
        acc0 = spread_high(acc0, half); s0 = spread_high(s0, half);
        acc1 = spread_high(acc1, half); s1 = spread_high(s1, half);
        acc2 = spread_high(acc2, half); s2 = spread_high(s2, half);
        acc3 = spread_high(acc3, half); s3 = spread_high(s3, half);

        // output: two head-pairs; low half does even head, high half odd head
        #pragma unroll
        for (int hp = 0; hp < 2; ++hp) {
            int hh = hp * 2 + half;
            const float* xr = nf + (size_t)n * 128 + hh * 32;
            float a = bw;
            #pragma unroll
            for (int k = 0; k < 32; ++k) a = fmaf(xr[k], wwreg[k], a);
            float accv = hp ? (half ? acc3 : acc2) : (half ? acc1 : acc0);
            float sv   = hp ? (half ? s3 : s2)     : (half ? s1 : s0);
            float f = (sv > 0.f) ? accv / sv : 0.f;
            out[(size_t)n * 128 + hp * 64 + lane] = lrelu(f + a);
        }
    }
}

extern "C" void kernel_launch(void* const* d_in, const int* in_sizes, int n_in,
                              void* d_out, int out_size, void* d_ws, size_t ws_size,
                              hipStream_t stream)
{
    const float* nf  = (const float*)d_in[0];
    const float* ef  = (const float*)d_in[1];
    const int*   src = (const int*)d_in[2];
    const int*   dst = (const int*)d_in[3];
    const float* Was = (const float*)d_in[4],  *bas = (const float*)d_in[5];
    const float* Wad = (const float*)d_in[6],  *bad = (const float*)d_in[7];
    const float* Wae = (const float*)d_in[8],  *bae = (const float*)d_in[9];
    const float* Wdot= (const float*)d_in[10];
    const float* Wms = (const float*)d_in[12], *bms = (const float*)d_in[13];
    const float* Wmd = (const float*)d_in[14], *bmd = (const float*)d_in[15];
    const float* Wme = (const float*)d_in[16], *bme = (const float*)d_in[17];
    const float* Wwn = (const float*)d_in[18], *bwn = (const float*)d_in[19];

    float* ws = (float*)d_ws;
    float* tab_s = ws;                                // V*256 f
    float* tab_d = tab_s + (size_t)V_N * 256;         // V*256 f
    int* qctr   = (int*)(tab_d + (size_t)V_N * 256);  // 1
    int* deg    = qctr + 1;                           // V
    int* rowptr = deg + V_N;                          // V+1
    int* cursor = rowptr + V_N + 1;                   // V
    int* eidx   = cursor + V_N;                       // E

    // zero qctr + deg in one shot (adjacent)
    hipMemsetAsync(qctr, 0, (V_N + 1) * sizeof(int), stream);

    const int ebk = (E_N + 255) / 256;                // 1954 blocks

    node_xform<<<512, 256, 0, stream>>>(nf, Was, bas, Wad, bad, Wms, bms, Wmd, bmd,
                                        tab_s, tab_d);
    hist_k<<<ebk, 256, 0, stream>>>(dst, deg);
    scan_k<<<1, 1024, 0, stream>>>(deg, rowptr, cursor);
    scatter_k<<<ebk, 256, 0, stream>>>(dst, cursor, eidx);
    node_gather<<<1024, 256, 0, stream>>>(ef, src, rowptr, eidx,
                                          Wae, bae, Wdot, Wme, bme, Wwn, bwn,
                                          nf, tab_s, tab_d, qctr, (float*)d_out);
}

// Round 8
// 414.717 us; speedup vs baseline: 1.2937x; 1.2937x over previous
//
#include <hip/hip_runtime.h>

#define V_N 30000
#define E_N 500000

__device__ __forceinline__ float lrelu(float x) { return fmaxf(x, 0.2f * x); }

// ---------------------------------------------------------------------------
// Kernel A: node transforms — 4 matrices fused (R5-proven).
// Output layout (gather-optimized, per node = 256 floats = 1 KB):
//   tab[node*256 + lane*8 + h]     = att value for head h, feature lane
//   tab[node*256 + lane*8 + 4 + h] = msg value for head h, feature lane
// ---------------------------------------------------------------------------
__global__ __launch_bounds__(256) void node_xform(
    const float* __restrict__ nf,
    const float* __restrict__ Was, const float* __restrict__ bas,
    const float* __restrict__ Wad, const float* __restrict__ bad,
    const float* __restrict__ Wms, const float* __restrict__ bms,
    const float* __restrict__ Wmd, const float* __restrict__ bmd,
    float* __restrict__ tab_s, float* __restrict__ tab_d)
{
    __shared__ float w0[1024], w1[1024], w2[1024], w3[1024];
    int tid = threadIdx.x;
    for (int i = tid; i < 1024; i += 256) {
        w0[i] = Was[i]; w1[i] = Wad[i];
        w2[i] = Wms[i]; w3[i] = Wmd[i];
    }
    __syncthreads();
    int lane = tid & 31;
    int r = blockIdx.x * 8 + (tid >> 5);          // r = node*4 + h
    if (r >= V_N * 4) return;                     // exact: never taken
    float x = nf[(size_t)r * 32 + lane];
    float a0 = bas[lane], a1 = bad[lane];
    float a2 = bms[lane], a3 = bmd[lane];
    #pragma unroll
    for (int k = 0; k < 32; ++k) {
        float xk = __shfl(x, k, 32);
        a0 += xk * w0[k * 32 + lane];
        a1 += xk * w1[k * 32 + lane];
        a2 += xk * w2[k * 32 + lane];
        a3 += xk * w3[k * 32 + lane];
    }
    int node = r >> 2, h = r & 3;
    size_t base = (size_t)node * 256 + lane * 8;
    tab_s[base + h]     = a0;   // att (src path)
    tab_s[base + 4 + h] = a2;   // msg (src path)
    tab_d[base + h]     = a1;   // att (dst path)
    tab_d[base + 4 + h] = a3;   // msg (dst path)
}

// ---------------------------------------------------------------------------
// CSR build: histogram -> exclusive scan -> scatter edge ids by dst. (R5)
// ---------------------------------------------------------------------------
__global__ __launch_bounds__(256) void hist_k(
    const int* __restrict__ dst, int* __restrict__ deg)
{
    int i = blockIdx.x * 256 + threadIdx.x;
    if (i < E_N) atomicAdd(&deg[dst[i]], 1);
}

__global__ __launch_bounds__(1024) void scan_k(
    const int* __restrict__ deg, int* __restrict__ rowptr, int* __restrict__ cursor)
{
    __shared__ int wsum[16];
    __shared__ int carry_s;
    int tid = threadIdx.x;
    int lane = tid & 63, wv = tid >> 6;
    if (tid == 0) carry_s = 0;
    __syncthreads();
    for (int base = 0; base < V_N; base += 1024) {
        int i = base + tid;
        int v = (i < V_N) ? deg[i] : 0;
        int x = v;
        #pragma unroll
        for (int off = 1; off < 64; off <<= 1) {
            int t = __shfl_up(x, off, 64);
            if (lane >= off) x += t;
        }
        if (lane == 63) wsum[wv] = x;
        __syncthreads();
        if (wv == 0 && lane < 16) {
            int s = wsum[lane];
            #pragma unroll
            for (int off = 1; off < 16; off <<= 1) {
                int t = __shfl_up(s, off, 64);
                if (lane >= off) s += t;
            }
            wsum[lane] = s;
        }
        __syncthreads();
        int woff  = (wv == 0) ? 0 : wsum[wv - 1];
        int carry = carry_s;
        int excl  = carry + woff + x - v;
        if (i < V_N) { rowptr[i] = excl; cursor[i] = excl; }
        __syncthreads();
        if (tid == 1023) carry_s = carry + wsum[15];
        __syncthreads();
    }
    if (tid == 0) rowptr[V_N] = carry_s;
}

__global__ __launch_bounds__(256) void scatter_k(
    const int* __restrict__ dst, int* __restrict__ cursor, int* __restrict__ eidx)
{
    int i = blockIdx.x * 256 + threadIdx.x;
    if (i < E_N) {
        int p = atomicAdd(&cursor[dst[i]], 1);
        eidx[p] = i;
    }
}

// ---------------------------------------------------------------------------
// Kernel B: per-dst aggregation + fused finalize. R5 structure verbatim
// (32-lane group per node, 8 nodes/block, next-edge prefetch, shfl broadcast
// GEMV, shfl_xor butterfly reduce). ONLY change vs R5: hot-loop weights
// Wae/Wme live in per-lane VGPR arrays (compile-time indexed) instead of LDS.
// ---------------------------------------------------------------------------
__global__ __launch_bounds__(256) void node_gather(
    const float* __restrict__ ef, const int* __restrict__ src,
    const int* __restrict__ rowptr, const int* __restrict__ eidx,
    const float* __restrict__ Wae, const float* __restrict__ bae,
    const float* __restrict__ Wdot, const float* __restrict__ bdot,
    const float* __restrict__ Wme, const float* __restrict__ bme,
    const float* __restrict__ Wwn, const float* __restrict__ bwn,
    const float* __restrict__ nf,
    const float* __restrict__ tab_s, const float* __restrict__ tab_d,
    float* __restrict__ out)
{
    __shared__ float ww[1024], wd[32];
    int tid = threadIdx.x;
    for (int i = tid; i < 1024; i += 256) ww[i] = Wwn[i];
    if (tid < 32) wd[tid] = Wdot[tid];
    __syncthreads();
    int lane = tid & 31;
    // hot-loop weights in registers (all indices compile-time after unroll)
    float wa[32], wm[32];
    #pragma unroll
    for (int k = 0; k < 32; ++k) {
        wa[k] = Wae[k * 32 + lane];
        wm[k] = Wme[k * 32 + lane];
    }
    float ba = bae[lane], bm = bme[lane];
    float wdl = wd[lane], bd = bdot[0];

    int n = blockIdx.x * 8 + (tid >> 5);             // 3750*8 = 30000 exact
    const float4* dp = (const float4*)(tab_d + (size_t)n * 256 + lane * 8);
    float4 da4 = dp[0], dm4 = dp[1];

    float acc0 = 0.f, acc1 = 0.f, acc2 = 0.f, acc3 = 0.f;
    float s0 = 0.f, s1 = 0.f, s2 = 0.f, s3 = 0.f;
    int p0 = rowptr[n], p1 = rowptr[n + 1];

    float4 ca4 = make_float4(0.f, 0.f, 0.f, 0.f), cm4 = ca4;
    float  xc  = 0.f;
    if (p0 < p1) {
        int e  = eidx[p0];
        int si = src[e];
        const float4* sp = (const float4*)(tab_s + (size_t)si * 256 + lane * 8);
        ca4 = sp[0]; cm4 = sp[1];
        xc  = ef[(size_t)e * 32 + lane];
    }
    for (int p = p0; p < p1; ++p) {
        float4 a4 = ca4, m4 = cm4;
        float  x  = xc;
        if (p + 1 < p1) {                            // prefetch next edge
            int en = eidx[p + 1];
            int sn = src[en];
            const float4* sp = (const float4*)(tab_s + (size_t)sn * 256 + lane * 8);
            ca4 = sp[0]; cm4 = sp[1];
            xc  = ef[(size_t)en * 32 + lane];
        }
        // edge GEMV: shfl broadcast of x, weights from VGPRs
        float ea = ba, me = bm;
        #pragma unroll
        for (int k = 0; k < 32; ++k) {
            float xk = __shfl(x, k, 32);
            ea = fmaf(xk, wa[k], ea);
            me = fmaf(xk, wm[k], me);
        }
        // scores per head, butterfly reduce over the 32-group
        float t0 = lrelu(a4.x + da4.x + ea) * wdl;
        float t1 = lrelu(a4.y + da4.y + ea) * wdl;
        float t2 = lrelu(a4.z + da4.z + ea) * wdl;
        float t3 = lrelu(a4.w + da4.w + ea) * wdl;
        #pragma unroll
        for (int off = 16; off; off >>= 1) {
            t0 += __shfl_xor(t0, off, 32);
            t1 += __shfl_xor(t1, off, 32);
            t2 += __shfl_xor(t2, off, 32);
            t3 += __shfl_xor(t3, off, 32);
        }
        float x0 = __expf(t0 + bd);
        float x1 = __expf(t1 + bd);
        float x2 = __expf(t2 + bd);
        float x3 = __expf(t3 + bd);
        float m0 = lrelu(m4.x + dm4.x + me);
        float m1 = lrelu(m4.y + dm4.y + me);
        float m2 = lrelu(m4.z + dm4.z + me);
        float m3 = lrelu(m4.w + dm4.w + me);
        acc0 = fmaf(x0, m0, acc0); s0 += x0;
        acc1 = fmaf(x1, m1, acc1); s1 += x1;
        acc2 = fmaf(x2, m2, acc2); s2 += x2;
        acc3 = fmaf(x3, m3, acc3); s3 += x3;
    }
    // fused finalize: out = lrelu(feat/ssum + nf@Wwn + bwn)
    #pragma unroll
    for (int h = 0; h < 4; ++h) {
        float x = nf[(size_t)n * 128 + h * 32 + lane];
        float a = bwn[lane];
        #pragma unroll
        for (int k = 0; k < 32; ++k) a = fmaf(__shfl(x, k, 32), ww[k * 32 + lane], a);
        float accv = (h == 0) ? acc0 : (h == 1) ? acc1 : (h == 2) ? acc2 : acc3;
        float sv   = (h == 0) ? s0   : (h == 1) ? s1   : (h == 2) ? s2   : s3;
        float f = (sv > 0.f) ? accv / sv : 0.f;
        out[(size_t)n * 128 + h * 32 + lane] = lrelu(f + a);
    }
}

extern "C" void kernel_launch(void* const* d_in, const int* in_sizes, int n_in,
                              void* d_out, int out_size, void* d_ws, size_t ws_size,
                              hipStream_t stream)
{
    const float* nf  = (const float*)d_in[0];
    const float* ef  = (const float*)d_in[1];
    const int*   src = (const int*)d_in[2];
    const int*   dst = (const int*)d_in[3];
    const float* Was = (const float*)d_in[4],  *bas = (const float*)d_in[5];
    const float* Wad = (const float*)d_in[6],  *bad = (const float*)d_in[7];
    const float* Wae = (const float*)d_in[8],  *bae = (const float*)d_in[9];
    const float* Wdot= (const float*)d_in[10], *bdot= (const float*)d_in[11];
    const float* Wms = (const float*)d_in[12], *bms = (const float*)d_in[13];
    const float* Wmd = (const float*)d_in[14], *bmd = (const float*)d_in[15];
    const float* Wme = (const float*)d_in[16], *bme = (const float*)d_in[17];
    const float* Wwn = (const float*)d_in[18], *bwn = (const float*)d_in[19];

    float* ws = (float*)d_ws;
    float* tab_s = ws;                                // V*256 f
    float* tab_d = tab_s + (size_t)V_N * 256;         // V*256 f
    int* deg    = (int*)(tab_d + (size_t)V_N * 256);  // V
    int* rowptr = deg + V_N;                          // V+1
    int* cursor = rowptr + V_N + 1;                   // V
    int* eidx   = cursor + V_N;                       // E

    hipMemsetAsync(deg, 0, V_N * sizeof(int), stream);

    const int rb  = (V_N * 4 + 7) / 8;                // 15000 blocks
    const int ebk = (E_N + 255) / 256;                // 1954 blocks
    const int nb  = (V_N + 7) / 8;                    // 3750 blocks

    node_xform<<<rb, 256, 0, stream>>>(nf, Was, bas, Wad, bad, Wms, bms, Wmd, bmd,
                                       tab_s, tab_d);
    hist_k<<<ebk, 256, 0, stream>>>(dst, deg);
    scan_k<<<1, 1024, 0, stream>>>(deg, rowptr, cursor);
    scatter_k<<<ebk, 256, 0, stream>>>(dst, cursor, eidx);
    node_gather<<<nb, 256, 0, stream>>>(ef, src, rowptr, eidx,
                                        Wae, bae, Wdot, bdot, Wme, bme, Wwn, bwn,
                                        nf, tab_s, tab_d, (float*)d_out);
}

// Round 9
// 367.937 us; speedup vs baseline: 1.4582x; 1.1271x over previous
//
#include <hip/hip_runtime.h>
#include <hip/hip_bf16.h>

#define V_N 30000
#define E_N 500000

__device__ __forceinline__ float lrelu(float x) { return fmaxf(x, 0.2f * x); }
__device__ __forceinline__ unsigned short f2bf(float f) {
    __hip_bfloat16 h = __float2bfloat16(f);
    return *reinterpret_cast<unsigned short*>(&h);
}
__device__ __forceinline__ float bf_lo(unsigned u) { return __uint_as_float(u << 16); }
__device__ __forceinline__ float bf_hi(unsigned u) { return __uint_as_float(u & 0xffff0000u); }

// ---------------------------------------------------------------------------
// Kernel A: src-side node transforms (Was, Wms), bf16-packed for 1-load gather.
// Layout per node: 32 lanes x uint4; lane's uint4 = {att0|att1, att2|att3,
// msg0|msg1, msg2|msg3} (bf16 pairs), feature = lane.
// ---------------------------------------------------------------------------
__global__ __launch_bounds__(256) void node_xform_s(
    const float* __restrict__ nf,
    const float* __restrict__ Was, const float* __restrict__ bas,
    const float* __restrict__ Wms, const float* __restrict__ bms,
    uint4* __restrict__ tab_s)
{
    __shared__ float w0[1024], w2[1024];
    int tid = threadIdx.x;
    for (int i = tid; i < 1024; i += 256) { w0[i] = Was[i]; w2[i] = Wms[i]; }
    __syncthreads();
    int lane = tid & 31;
    int n = blockIdx.x * 8 + (tid >> 5);          // 3750*8 = 30000 exact
    float att[4], msg[4];
    #pragma unroll
    for (int h = 0; h < 4; ++h) {
        float x = nf[(size_t)n * 128 + h * 32 + lane];
        float a0 = bas[lane], a2 = bms[lane];
        #pragma unroll
        for (int k = 0; k < 32; ++k) {
            float xk = __shfl(x, k, 32);
            a0 = fmaf(xk, w0[k * 32 + lane], a0);
            a2 = fmaf(xk, w2[k * 32 + lane], a2);
        }
        att[h] = a0; msg[h] = a2;
    }
    uint4 u;
    u.x = f2bf(att[0]) | ((unsigned)f2bf(att[1]) << 16);
    u.y = f2bf(att[2]) | ((unsigned)f2bf(att[3]) << 16);
    u.z = f2bf(msg[0]) | ((unsigned)f2bf(msg[1]) << 16);
    u.w = f2bf(msg[2]) | ((unsigned)f2bf(msg[3]) << 16);
    tab_s[(size_t)n * 32 + lane] = u;
}

// ---------------------------------------------------------------------------
// CSR build: histogram -> exclusive scan -> scatter (records pos[e], csr_src).
// ---------------------------------------------------------------------------
__global__ __launch_bounds__(256) void hist_k(
    const int* __restrict__ dst, int* __restrict__ deg)
{
    int i = blockIdx.x * 256 + threadIdx.x;
    if (i < E_N) atomicAdd(&deg[dst[i]], 1);
}

__global__ __launch_bounds__(1024) void scan_k(
    const int* __restrict__ deg, int* __restrict__ rowptr, int* __restrict__ cursor)
{
    __shared__ int wsum[16];
    __shared__ int carry_s;
    int tid = threadIdx.x;
    int lane = tid & 63, wv = tid >> 6;
    if (tid == 0) carry_s = 0;
    __syncthreads();
    for (int base = 0; base < V_N; base += 1024) {
        int i = base + tid;
        int v = (i < V_N) ? deg[i] : 0;
        int x = v;
        #pragma unroll
        for (int off = 1; off < 64; off <<= 1) {
            int t = __shfl_up(x, off, 64);
            if (lane >= off) x += t;
        }
        if (lane == 63) wsum[wv] = x;
        __syncthreads();
        if (wv == 0 && lane < 16) {
            int s = wsum[lane];
            #pragma unroll
            for (int off = 1; off < 16; off <<= 1) {
                int t = __shfl_up(s, off, 64);
                if (lane >= off) s += t;
            }
            wsum[lane] = s;
        }
        __syncthreads();
        int woff  = (wv == 0) ? 0 : wsum[wv - 1];
        int carry = carry_s;
        int excl  = carry + woff + x - v;
        if (i < V_N) { rowptr[i] = excl; cursor[i] = excl; }
        __syncthreads();
        if (tid == 1023) carry_s = carry + wsum[15];
        __syncthreads();
    }
    if (tid == 0) rowptr[V_N] = carry_s;
}

__global__ __launch_bounds__(256) void scatter_k(
    const int* __restrict__ dst, const int* __restrict__ src,
    int* __restrict__ cursor, int* __restrict__ pos, int* __restrict__ csr_src)
{
    int i = blockIdx.x * 256 + threadIdx.x;
    if (i < E_N) {
        int p = atomicAdd(&cursor[dst[i]], 1);
        pos[i] = p;
        csr_src[p] = src[i];
    }
}

// ---------------------------------------------------------------------------
// Kernel B: STREAMING edge GEMV (coalesced ef, no gathers). Computes
// ea = ef@Wae+bae, me = ef@Wme+bme; writes bf16-packed at CSR slot pos[e]
// (128B full-line scattered writes). R5-proven shfl+LDS GEMV pattern.
// ---------------------------------------------------------------------------
__global__ __launch_bounds__(256) void edge_gemv(
    const float* __restrict__ ef, const int* __restrict__ pos,
    const float* __restrict__ Wae, const float* __restrict__ bae,
    const float* __restrict__ Wme, const float* __restrict__ bme,
    unsigned* __restrict__ em)
{
    __shared__ float wa[1024], wm[1024];
    int tid = threadIdx.x;
    for (int i = tid; i < 1024; i += 256) { wa[i] = Wae[i]; wm[i] = Wme[i]; }
    __syncthreads();
    int lane = tid & 31;
    int gid = (blockIdx.x * 256 + tid) >> 5;
    int ngr = (gridDim.x * 256) >> 5;
    float ba = bae[lane], bm = bme[lane];
    for (int e = gid; e < E_N; e += ngr) {
        float x = ef[(size_t)e * 32 + lane];
        int p = pos[e];
        float ea = ba, me = bm;
        #pragma unroll
        for (int k = 0; k < 32; ++k) {
            float xk = __shfl(x, k, 32);
            ea = fmaf(xk, wa[k * 32 + lane], ea);
            me = fmaf(xk, wm[k * 32 + lane], me);
        }
        em[(size_t)p * 32 + lane] = f2bf(ea) | ((unsigned)f2bf(me) << 16);
    }
}

// ---------------------------------------------------------------------------
// Kernel C: per-dst aggregation, slim loop (no in-loop GEMV).
// Prologue per node: dst-side transforms (Wad, Wmd) + Wwn GEMV, in registers.
// Loop per edge: csr_src (seq) + tab_s (1 gathered b128) + em (seq b32),
// butterfly score reduce, exp, accumulate. b_dot kept (R5-proven).
// ---------------------------------------------------------------------------
__global__ __launch_bounds__(256) void node_gather2(
    const int* __restrict__ rowptr, const int* __restrict__ csr_src,
    const unsigned* __restrict__ em, const uint4* __restrict__ tab_s,
    const float* __restrict__ Wad, const float* __restrict__ bad,
    const float* __restrict__ Wmd, const float* __restrict__ bmd,
    const float* __restrict__ Wdot, const float* __restrict__ bdot,
    const float* __restrict__ Wwn, const float* __restrict__ bwn,
    const float* __restrict__ nf,
    float* __restrict__ out)
{
    __shared__ float w1[1024], w3[1024], ww[1024], wd[32];
    int tid = threadIdx.x;
    for (int i = tid; i < 1024; i += 256) { w1[i] = Wad[i]; w3[i] = Wmd[i]; ww[i] = Wwn[i]; }
    if (tid < 32) wd[tid] = Wdot[tid];
    __syncthreads();
    int lane = tid & 31;
    int n = blockIdx.x * 8 + (tid >> 5);          // 3750*8 = 30000 exact
    float wdl = wd[lane], bd = bdot[0];

    // per-node prologue: da/dm (dst transforms) + wn (Wwn path), all heads
    float da[4], dm[4], wn[4];
    #pragma unroll
    for (int h = 0; h < 4; ++h) {
        float x = nf[(size_t)n * 128 + h * 32 + lane];
        float a1 = bad[lane], a3 = bmd[lane], aw = bwn[lane];
        #pragma unroll
        for (int k = 0; k < 32; ++k) {
            float xk = __shfl(x, k, 32);
            a1 = fmaf(xk, w1[k * 32 + lane], a1);
            a3 = fmaf(xk, w3[k * 32 + lane], a3);
            aw = fmaf(xk, ww[k * 32 + lane], aw);
        }
        da[h] = a1; dm[h] = a3; wn[h] = aw;
    }

    float acc0 = 0.f, acc1 = 0.f, acc2 = 0.f, acc3 = 0.f;
    float s0 = 0.f, s1 = 0.f, s2 = 0.f, s3 = 0.f;
    int p0 = rowptr[n], p1 = rowptr[n + 1];

    uint4 gc = make_uint4(0, 0, 0, 0);
    unsigned ec = 0;
    if (p0 < p1) {
        int si = csr_src[p0];
        gc = tab_s[(size_t)si * 32 + lane];
        ec = em[(size_t)p0 * 32 + lane];
    }
    for (int p = p0; p < p1; ++p) {
        uint4 g = gc; unsigned ev = ec;
        if (p + 1 < p1) {                          // prefetch next edge
            int sn = csr_src[p + 1];
            gc = tab_s[(size_t)sn * 32 + lane];
            ec = em[(size_t)(p + 1) * 32 + lane];
        }
        float ea = bf_lo(ev), me = bf_hi(ev);
        float t0 = lrelu(bf_lo(g.x) + da[0] + ea) * wdl;
        float t1 = lrelu(bf_hi(g.x) + da[1] + ea) * wdl;
        float t2 = lrelu(bf_lo(g.y) + da[2] + ea) * wdl;
        float t3 = lrelu(bf_hi(g.y) + da[3] + ea) * wdl;
        #pragma unroll
        for (int off = 16; off; off >>= 1) {
            t0 += __shfl_xor(t0, off, 32);
            t1 += __shfl_xor(t1, off, 32);
            t2 += __shfl_xor(t2, off, 32);
            t3 += __shfl_xor(t3, off, 32);
        }
        float x0 = __expf(t0 + bd), x1 = __expf(t1 + bd);
        float x2 = __expf(t2 + bd), x3 = __expf(t3 + bd);
        float m0 = lrelu(bf_lo(g.z) + dm[0] + me);
        float m1 = lrelu(bf_hi(g.z) + dm[1] + me);
        float m2 = lrelu(bf_lo(g.w) + dm[2] + me);
        float m3 = lrelu(bf_hi(g.w) + dm[3] + me);
        acc0 = fmaf(x0, m0, acc0); s0 += x0;
        acc1 = fmaf(x1, m1, acc1); s1 += x1;
        acc2 = fmaf(x2, m2, acc2); s2 += x2;
        acc3 = fmaf(x3, m3, acc3); s3 += x3;
    }
    // epilogue: out = lrelu(feat/ssum + wn)
    #pragma unroll
    for (int h = 0; h < 4; ++h) {
        float accv = (h == 0) ? acc0 : (h == 1) ? acc1 : (h == 2) ? acc2 : acc3;
        float sv   = (h == 0) ? s0   : (h == 1) ? s1   : (h == 2) ? s2   : s3;
        float f = (sv > 0.f) ? accv / sv : 0.f;
        out[(size_t)n * 128 + h * 32 + lane] = lrelu(f + wn[h]);
    }
}

extern "C" void kernel_launch(void* const* d_in, const int* in_sizes, int n_in,
                              void* d_out, int out_size, void* d_ws, size_t ws_size,
                              hipStream_t stream)
{
    const float* nf  = (const float*)d_in[0];
    const float* ef  = (const float*)d_in[1];
    const int*   src = (const int*)d_in[2];
    const int*   dst = (const int*)d_in[3];
    const float* Was = (const float*)d_in[4],  *bas = (const float*)d_in[5];
    const float* Wad = (const float*)d_in[6],  *bad = (const float*)d_in[7];
    const float* Wae = (const float*)d_in[8],  *bae = (const float*)d_in[9];
    const float* Wdot= (const float*)d_in[10], *bdot= (const float*)d_in[11];
    const float* Wms = (const float*)d_in[12], *bms = (const float*)d_in[13];
    const float* Wmd = (const float*)d_in[14], *bmd = (const float*)d_in[15];
    const float* Wme = (const float*)d_in[16], *bme = (const float*)d_in[17];
    const float* Wwn = (const float*)d_in[18], *bwn = (const float*)d_in[19];

    // ws layout (83.7 MB total):
    unsigned* em   = (unsigned*)d_ws;                       // E*32 u32 = 64 MB
    uint4*  tab_s  = (uint4*)(em + (size_t)E_N * 32);       // V*32 uint4 = 15.36 MB
    int*    deg    = (int*)((char*)tab_s + (size_t)V_N * 512); // V
    int*    rowptr = deg + V_N;                             // V+1
    int*    cursor = rowptr + V_N + 1;                      // V
    int*    pos    = cursor + V_N;                          // E
    int*    csr_src= pos + E_N;                             // E

    hipMemsetAsync(deg, 0, V_N * sizeof(int), stream);

    const int ebk = (E_N + 255) / 256;                      // 1954 blocks
    const int nb  = V_N / 8;                                // 3750 blocks

    node_xform_s<<<nb, 256, 0, stream>>>(nf, Was, bas, Wms, bms, tab_s);
    hist_k<<<ebk, 256, 0, stream>>>(dst, deg);
    scan_k<<<1, 1024, 0, stream>>>(deg, rowptr, cursor);
    scatter_k<<<ebk, 256, 0, stream>>>(dst, src, cursor, pos, csr_src);
    edge_gemv<<<4096, 256, 0, stream>>>(ef, pos, Wae, bae, Wme, bme, em);
    node_gather2<<<nb, 256, 0, stream>>>(rowptr, csr_src, em, tab_s,
                                         Wad, bad, Wmd, bmd, Wdot, bdot, Wwn, bwn,
                                         nf, (float*)d_out);
}